// Round 4
// baseline (44500.308 us; speedup 1.0000x reference)
//
#include <hip/hip_runtime.h>
#include <hip/hip_cooperative_groups.h>

namespace cg = cooperative_groups;

// DrosophilaOpticLobeCircuit: 100-step recurrent sparse circuit.
// R4: coalesced gather. One WAVE per neuron: lane = (edge_slot cl=lane>>3,
// batch b=lane&7). Each 8-lane cluster reads one r-row (32B contiguous);
// wave's CSR read is 8 consecutive int2 (one 64B line). Distinct cache lines
// per gather instruction: 8 (was 64). Batch reduce = 3-shuffle allreduce.
// Persistent cooperative kernel, grid.sync per step; multi-launch fallback.

#define BLK 256
#define STEPS 100
#define NBATCH 8
static constexpr float DT_C = 0.1f;

__global__ void k_zero(int* counts, int* tm1_pos, int N) {
    int i = blockIdx.x * BLK + threadIdx.x;
    if (i < N) { counts[i] = 0; tm1_pos[i] = -1; }
}

__global__ void k_tm1pos(const int* __restrict__ tm1_idx, int* tm1_pos, int NT) {
    int i = blockIdx.x * BLK + threadIdx.x;
    if (i < NT) tm1_pos[tm1_idx[i]] = i;
}

__global__ void k_hist(const int* __restrict__ tgt, int* counts, int E) {
    int i = blockIdx.x * BLK + threadIdx.x;
    if (i < E) atomicAdd(&counts[tgt[i]], 1);
}

__global__ void k_scan1(const int* __restrict__ counts, int* offsets, int* bsum, int N) {
    __shared__ int s[BLK];
    int tx = threadIdx.x;
    int i = blockIdx.x * BLK + tx;
    int v = (i < N) ? counts[i] : 0;
    s[tx] = v; __syncthreads();
    for (int d = 1; d < BLK; d <<= 1) {
        int t = (tx >= d) ? s[tx - d] : 0;
        __syncthreads();
        s[tx] += t;
        __syncthreads();
    }
    if (i < N) offsets[i] = s[tx] - v;
    if (tx == BLK - 1) bsum[blockIdx.x] = s[tx];
}

__global__ void k_scan2(int* bsum, int nb) {
    __shared__ int s[BLK];
    int tx = threadIdx.x;
    int v = (tx < nb) ? bsum[tx] : 0;
    s[tx] = v; __syncthreads();
    for (int d = 1; d < BLK; d <<= 1) {
        int t = (tx >= d) ? s[tx - d] : 0;
        __syncthreads();
        s[tx] += t;
        __syncthreads();
    }
    if (tx < nb) bsum[tx] = s[tx] - v;
}

__global__ void k_scan3(const int* __restrict__ bsum, int* offsets, int* cursor, int N, int E) {
    int i = blockIdx.x * BLK + threadIdx.x;
    if (i < N) {
        int o = offsets[i] + bsum[i >> 8];
        offsets[i] = o;
        cursor[i] = o;
    } else if (i == N) {
        offsets[N] = E;
    }
}

__global__ void k_fill(const int* __restrict__ srcI, const int* __restrict__ tgtI,
                       const float* __restrict__ w,
                       const float* __restrict__ se, const float* __restrict__ si,
                       int* cursor, int2* __restrict__ csr, int E) {
    int i = blockIdx.x * BLK + threadIdx.x;
    if (i >= E) return;
    float wv = w[i];
    float sc = wv > 0.f ? se[0] : (wv < 0.f ? si[0] : 1.f);
    float sw = wv * sc;
    int t = tgtI[i];
    int pos = atomicAdd(&cursor[t], 1);
    csr[pos] = make_int2(srcI[i], __float_as_int(sw));
}

// init v_w[N][8], r0=r1=relu(v), per-neuron coefficients (cA,cB,cC,tm1flag)
__global__ void k_initv(const float* __restrict__ tm1_in, const float* __restrict__ v_init,
                        const float* __restrict__ bias, const float* __restrict__ tau_p,
                        const int* __restrict__ type_ids, const int* __restrict__ tm1_pos,
                        float* __restrict__ v_w, float* __restrict__ r0, float* __restrict__ r1,
                        float4* __restrict__ coef, int N, int NT) {
    int n = blockIdx.x * BLK + threadIdx.x;
    if (n >= N) return;
    int k = tm1_pos[n];
    float tau = tau_p[type_ids[n]];
    float g = DT_C / tau;
    coef[n] = make_float4(1.f - g, g, bias[n] * g, (k >= 0) ? 1.f : 0.f);
    float vv[NBATCH], rr[NBATCH];
    for (int b = 0; b < NBATCH; ++b) {
        float val = (k >= 0) ? tm1_in[b * NT + k] : v_init[b * N + n];
        vv[b] = val;
        rr[b] = fmaxf(val, 0.f);
    }
    float4* vp = (float4*)(v_w + (size_t)n * 8);
    float4* r0p = (float4*)(r0 + (size_t)n * 8);
    float4* r1p = (float4*)(r1 + (size_t)n * 8);
    vp[0]  = make_float4(vv[0], vv[1], vv[2], vv[3]);
    vp[1]  = make_float4(vv[4], vv[5], vv[6], vv[7]);
    float4 rlo = make_float4(rr[0], rr[1], rr[2], rr[3]);
    float4 rhi = make_float4(rr[4], rr[5], rr[6], rr[7]);
    r0p[0] = rlo; r0p[1] = rhi;
    r1p[0] = rlo; r1p[1] = rhi;
}

// wave-per-neuron step body: lane = (cl=lane>>3 edge slot, b=lane&7 batch).
// 8-lane cluster cl reads csr[base+cl] (same addr within cluster -> merged;
// 8 clusters -> 8 consecutive int2 = one 64B line per wave) and gathers
// rp[src*8 + b] (32B contiguous per cluster). 3-shuffle allreduce over
// clusters leaves every lane with syn for its batch b.
__device__ __forceinline__ void step_neuron(
        int n, int lane, int cl, int b,
        const int* __restrict__ offsets, const int2* __restrict__ csr,
        const float4* __restrict__ coef, const float* __restrict__ rp,
        float* __restrict__ v_w, float* __restrict__ rn) {
    float4 cf = coef[n];
    if (cf.w != 0.f) return;                 // Tm1 row: clamped, r constant
    int s = offsets[n], e = offsets[n + 1];
    float acc = 0.f;
    int nedge = e - s;
    int nfull = nedge & ~7;                  // full 8-edge blocks
    int base = s;
    for (; base < s + nfull; base += 8) {
        int2 ew = csr[base + cl];
        acc = fmaf(__int_as_float(ew.y), rp[(size_t)ew.x * 8 + b], acc);
    }
    if (base + cl < e) {                     // tail (partial cluster set)
        int2 ew = csr[base + cl];
        acc = fmaf(__int_as_float(ew.y), rp[(size_t)ew.x * 8 + b], acc);
    }
    acc += __shfl_xor(acc, 8);
    acc += __shfl_xor(acc, 16);
    acc += __shfl_xor(acc, 32);              // all lanes: syn for batch b
    if (lane < 8) {
        size_t ix = (size_t)n * 8 + b;
        float vn = v_w[ix] * cf.x + acc * cf.y + cf.z;
        v_w[ix] = vn;
        rn[ix] = fmaxf(vn, 0.f);
    }
}

// ---------------- persistent cooperative path ----------------
__global__ __launch_bounds__(BLK, 4) void k_run_p(
        const int* __restrict__ offsets, const int2* __restrict__ csr,
        const float4* __restrict__ coef,
        float* __restrict__ v_w, float* __restrict__ r0, float* __restrict__ r1,
        int N) {
    cg::grid_group grid = cg::this_grid();
    const int gtid   = blockIdx.x * BLK + threadIdx.x;
    const int wave   = gtid >> 6;
    const int lane   = threadIdx.x & 63;
    const int cl     = lane >> 3;
    const int b      = lane & 7;
    const int nWaves = (gridDim.x * BLK) >> 6;

    float* rp = r0;
    float* rn = r1;
    for (int step = 0; step < STEPS; ++step) {
        for (int n = wave; n < N; n += nWaves)
            step_neuron(n, lane, cl, b, offsets, csr, coef, rp, v_w, rn);
        __threadfence();
        grid.sync();
        float* t = rp; rp = rn; rn = t;
    }
}

// ---------------- fallback multi-launch path ----------------
__global__ __launch_bounds__(BLK) void k_step_w(
        const int* __restrict__ offsets, const int2* __restrict__ csr,
        const float4* __restrict__ coef, const float* __restrict__ r_prev,
        float* __restrict__ v_w, float* __restrict__ r_next, int N) {
    int wave = (blockIdx.x * BLK + threadIdx.x) >> 6;
    int lane = threadIdx.x & 63;
    if (wave >= N) return;
    step_neuron(wave, lane, lane >> 3, lane & 7, offsets, csr, coef,
                r_prev, v_w, r_next);
}

__global__ void k_out(const float* __restrict__ v_w, float* __restrict__ out, int N) {
    int t = blockIdx.x * BLK + threadIdx.x;
    if (t >= NBATCH * N) return;
    int b = t / N;
    int n = t - b * N;
    out[t] = v_w[(size_t)n * 8 + b];
}

static inline size_t align16(size_t x) { return (x + 15) & ~(size_t)15; }

extern "C" void kernel_launch(void* const* d_in, const int* in_sizes, int n_in,
                              void* d_out, int out_size, void* d_ws, size_t ws_size,
                              hipStream_t stream) {
    const float* tm1_in  = (const float*)d_in[0];
    const float* v_init  = (const float*)d_in[1];
    const float* weights = (const float*)d_in[2];
    const float* bias    = (const float*)d_in[3];
    const float* tau_p   = (const float*)d_in[4];
    const float* se      = (const float*)d_in[5];
    const float* si      = (const float*)d_in[6];
    const int*   srcI    = (const int*)d_in[7];
    const int*   tgtI    = (const int*)d_in[8];
    const int*   type_ids= (const int*)d_in[9];
    const int*   tm1_idx = (const int*)d_in[10];

    const int E  = in_sizes[2];
    const int N  = in_sizes[3];
    const int NT = in_sizes[10];

    char* p = (char*)d_ws;
    size_t off = 0;
    auto take = [&](size_t bytes) { void* r = p + off; off += align16(bytes); return r; };
    int*    offsets = (int*)   take((size_t)(N + 1) * 4);
    int*    cursor  = (int*)   take((size_t)N * 4);
    int*    counts  = (int*)   take((size_t)N * 4);
    int*    tm1_pos = (int*)   take((size_t)N * 4);
    int*    bsum    = (int*)   take(1024 * 4);
    int2*   csr     = (int2*)  take((size_t)E * 8);
    float4* coef    = (float4*)take((size_t)N * 16);
    float*  v_w     = (float*) take((size_t)N * 8 * 4);
    float*  r0      = (float*) take((size_t)N * 8 * 4);
    float*  r1      = (float*) take((size_t)N * 8 * 4);
    (void)ws_size;

    const int gN  = (N + BLK - 1) / BLK;
    const int gN1 = (N + 1 + BLK - 1) / BLK;
    const int gE  = (E + BLK - 1) / BLK;
    const int gNT = (NT + BLK - 1) / BLK;
    const int gS  = (N * NBATCH + BLK - 1) / BLK;

    k_zero<<<gN, BLK, 0, stream>>>(counts, tm1_pos, N);
    k_tm1pos<<<gNT, BLK, 0, stream>>>(tm1_idx, tm1_pos, NT);
    k_hist<<<gE, BLK, 0, stream>>>(tgtI, counts, E);
    k_scan1<<<gN, BLK, 0, stream>>>(counts, offsets, bsum, N);
    k_scan2<<<1, BLK, 0, stream>>>(bsum, gN);
    k_scan3<<<gN1, BLK, 0, stream>>>(bsum, offsets, cursor, N, E);
    k_fill<<<gE, BLK, 0, stream>>>(srcI, tgtI, weights, se, si, cursor, csr, E);
    k_initv<<<gN, BLK, 0, stream>>>(tm1_in, v_init, bias, tau_p, type_ids, tm1_pos,
                                    v_w, r0, r1, coef, N, NT);

    // ---- cooperative persistent attempt (checked) ----
    bool coop_done = false;
    int occ = 0, dev = 0, nCU = 0;
    if (hipGetDevice(&dev) == hipSuccess &&
        hipDeviceGetAttribute(&nCU, hipDeviceAttributeMultiprocessorCount, dev) == hipSuccess &&
        hipOccupancyMaxActiveBlocksPerMultiprocessor(&occ, (const void*)k_run_p, BLK, 0) == hipSuccess &&
        occ >= 1) {
        int maxBlocks  = occ * nCU;
        int needBlocks = (N + (BLK / 64) - 1) / (BLK / 64);   // 1 wave per neuron
        int blocks = maxBlocks < needBlocks ? maxBlocks : needBlocks;
        int Nv = N;
        void* args[] = { &offsets, &csr, &coef, &v_w, &r0, &r1, &Nv };
        hipError_t e = hipLaunchCooperativeKernel((const void*)k_run_p, dim3(blocks),
                                                  dim3(BLK), args, 0, stream);
        coop_done = (e == hipSuccess);
    }

    // ---- fallback: multi-launch, same wave-per-neuron body ----
    if (!coop_done) {
        int blocks = (N * 64 + BLK - 1) / BLK;
        float* rb[2] = { r0, r1 };
        for (int s = 0; s < STEPS; ++s) {
            k_step_w<<<blocks, BLK, 0, stream>>>(offsets, csr, coef, rb[s & 1],
                                                 v_w, rb[(s + 1) & 1], N);
        }
    }
    k_out<<<gS, BLK, 0, stream>>>(v_w, (float*)d_out, N);
}

// Round 5
// 1242.197 us; speedup vs baseline: 35.8239x; 35.8239x over previous
//
#include <hip/hip_runtime.h>

// DrosophilaOpticLobeCircuit: 100-step recurrent sparse circuit.
// R5: R1-proven multi-launch structure + compressed data paths.
//  - CSR entry: 4B = src:u16 (N<65536) | weight:bf16 in high 16 bits
//    (unpack = AND 0xFFFF0000 -> fp32, free).
//  - r (relu state): bf16 rows of 8 batches = 16B -> ONE uint4 gather per
//    edge (was 2x float4); halves TA line-work, r buffers 1.5MB -> 0.75MB.
//  - v stays fp32; accumulation fp32; only storage of r/w is bf16 (RNE).
// Layout: batch-inner [N][8]; 8-lane group per neuron, lane = edge-slot and
// batch id; butterfly transpose-reduce leaves lane b with batch-b sum.

#define BLK 256
#define STEPS 100
#define NBATCH 8
static constexpr float DT_C = 0.1f;

__device__ __forceinline__ unsigned f2bf_rne(float x) {   // fp32 -> bf16 bits (RNE)
    unsigned u = __float_as_uint(x);
    return (u + 0x7FFFu + ((u >> 16) & 1u)) >> 16;
}
__device__ __forceinline__ unsigned pk_bf2(float a, float b) {
    return f2bf_rne(a) | (f2bf_rne(b) << 16);
}

__global__ void k_zero(int* counts, int* tm1_pos, int N) {
    int i = blockIdx.x * BLK + threadIdx.x;
    if (i < N) { counts[i] = 0; tm1_pos[i] = -1; }
}

__global__ void k_tm1pos(const int* __restrict__ tm1_idx, int* tm1_pos, int NT) {
    int i = blockIdx.x * BLK + threadIdx.x;
    if (i < NT) tm1_pos[tm1_idx[i]] = i;
}

__global__ void k_hist(const int* __restrict__ tgt, int* counts, int E) {
    int i = blockIdx.x * BLK + threadIdx.x;
    if (i < E) atomicAdd(&counts[tgt[i]], 1);
}

__global__ void k_scan1(const int* __restrict__ counts, int* offsets, int* bsum, int N) {
    __shared__ int s[BLK];
    int tx = threadIdx.x;
    int i = blockIdx.x * BLK + tx;
    int v = (i < N) ? counts[i] : 0;
    s[tx] = v; __syncthreads();
    for (int d = 1; d < BLK; d <<= 1) {
        int t = (tx >= d) ? s[tx - d] : 0;
        __syncthreads();
        s[tx] += t;
        __syncthreads();
    }
    if (i < N) offsets[i] = s[tx] - v;
    if (tx == BLK - 1) bsum[blockIdx.x] = s[tx];
}

__global__ void k_scan2(int* bsum, int nb) {
    __shared__ int s[BLK];
    int tx = threadIdx.x;
    int v = (tx < nb) ? bsum[tx] : 0;
    s[tx] = v; __syncthreads();
    for (int d = 1; d < BLK; d <<= 1) {
        int t = (tx >= d) ? s[tx - d] : 0;
        __syncthreads();
        s[tx] += t;
        __syncthreads();
    }
    if (tx < nb) bsum[tx] = s[tx] - v;
}

__global__ void k_scan3(const int* __restrict__ bsum, int* offsets, int* cursor, int N, int E) {
    int i = blockIdx.x * BLK + threadIdx.x;
    if (i < N) {
        int o = offsets[i] + bsum[i >> 8];
        offsets[i] = o;
        cursor[i] = o;
    } else if (i == N) {
        offsets[N] = E;
    }
}

// CSR fill: entry = (bf16(w*scale) << 16) | src_u16
__global__ void k_fill(const int* __restrict__ srcI, const int* __restrict__ tgtI,
                       const float* __restrict__ w,
                       const float* __restrict__ se, const float* __restrict__ si,
                       int* cursor, unsigned* __restrict__ csr, int E) {
    int i = blockIdx.x * BLK + threadIdx.x;
    if (i >= E) return;
    float wv = w[i];
    float sc = wv > 0.f ? se[0] : (wv < 0.f ? si[0] : 1.f);
    float sw = wv * sc;
    unsigned entry = (f2bf_rne(sw) << 16) | (unsigned)srcI[i];
    int t = tgtI[i];
    int pos = atomicAdd(&cursor[t], 1);
    csr[pos] = entry;
}

// init v_w[N][8] (fp32), r0=r1 = bf16 rows, per-neuron coef (cA,cB,cC,tm1flag)
__global__ void k_initv(const float* __restrict__ tm1_in, const float* __restrict__ v_init,
                        const float* __restrict__ bias, const float* __restrict__ tau_p,
                        const int* __restrict__ type_ids, const int* __restrict__ tm1_pos,
                        float* __restrict__ v_w, uint4* __restrict__ r0, uint4* __restrict__ r1,
                        float4* __restrict__ coef, int N, int NT) {
    int n = blockIdx.x * BLK + threadIdx.x;
    if (n >= N) return;
    int k = tm1_pos[n];
    float tau = tau_p[type_ids[n]];
    float g = DT_C / tau;
    coef[n] = make_float4(1.f - g, g, bias[n] * g, (k >= 0) ? 1.f : 0.f);
    float vv[NBATCH], rr[NBATCH];
    for (int b = 0; b < NBATCH; ++b) {
        float val = (k >= 0) ? tm1_in[b * NT + k] : v_init[b * N + n];
        vv[b] = val;
        rr[b] = fmaxf(val, 0.f);
    }
    float4* vp = (float4*)(v_w + (size_t)n * 8);
    vp[0] = make_float4(vv[0], vv[1], vv[2], vv[3]);
    vp[1] = make_float4(vv[4], vv[5], vv[6], vv[7]);
    uint4 rq = make_uint4(pk_bf2(rr[0], rr[1]), pk_bf2(rr[2], rr[3]),
                          pk_bf2(rr[4], rr[5]), pk_bf2(rr[6], rr[7]));
    r0[n] = rq;
    r1[n] = rq;
}

// 8-lane-group butterfly transpose-reduce: a0/a1 hold 8 batch partials per
// lane; returns lane sub's full sum for batch==sub.
__device__ __forceinline__ float butterfly8(float4 a0, float4 a1, int sub) {
    int bit0 = sub & 1, bit1 = (sub >> 1) & 1, bit2 = (sub >> 2) & 1;
    float b0 = (bit0 ? a0.y : a0.x) + __shfl_xor(bit0 ? a0.x : a0.y, 1);
    float b1 = (bit0 ? a0.w : a0.z) + __shfl_xor(bit0 ? a0.z : a0.w, 1);
    float b2 = (bit0 ? a1.y : a1.x) + __shfl_xor(bit0 ? a1.x : a1.y, 1);
    float b3 = (bit0 ? a1.w : a1.z) + __shfl_xor(bit0 ? a1.z : a1.w, 1);
    float c0 = (bit1 ? b1 : b0) + __shfl_xor(bit1 ? b0 : b1, 2);
    float c1 = (bit1 ? b3 : b2) + __shfl_xor(bit1 ? b2 : b3, 2);
    return (bit2 ? c1 : c0) + __shfl_xor(bit2 ? c0 : c1, 4);
}

// one 8-lane group per target neuron; lane sub strides edges (4B csr entry,
// 16B bf16 row gather), accumulates 8 batch partials in fp32, butterfly
// reduces, updates v (fp32) and stores r_next (bf16, 2B/lane = 16B/group).
__global__ __launch_bounds__(BLK) void k_step(
        const int* __restrict__ offsets, const unsigned* __restrict__ csr,
        const float4* __restrict__ coef, const uint4* __restrict__ r_prev,
        float* __restrict__ v_w, unsigned short* __restrict__ r_next, int N) {
    int tid = blockIdx.x * BLK + threadIdx.x;
    int n = tid >> 3;
    int sub = threadIdx.x & 7;
    if (n >= N) return;
    float4 cf = coef[n];
    if (cf.w != 0.f) return;                 // Tm1 row: clamped, r constant
    int s = offsets[n], e = offsets[n + 1];
    float4 a0 = make_float4(0.f, 0.f, 0.f, 0.f);
    float4 a1 = make_float4(0.f, 0.f, 0.f, 0.f);
    for (int i = s + sub; i < e; i += 8) {
        unsigned ew = csr[i];
        float w = __uint_as_float(ew & 0xFFFF0000u);
        uint4 q = r_prev[ew & 0xFFFFu];
        a0.x = fmaf(w, __uint_as_float(q.x << 16),          a0.x);
        a0.y = fmaf(w, __uint_as_float(q.x & 0xFFFF0000u),  a0.y);
        a0.z = fmaf(w, __uint_as_float(q.y << 16),          a0.z);
        a0.w = fmaf(w, __uint_as_float(q.y & 0xFFFF0000u),  a0.w);
        a1.x = fmaf(w, __uint_as_float(q.z << 16),          a1.x);
        a1.y = fmaf(w, __uint_as_float(q.z & 0xFFFF0000u),  a1.y);
        a1.z = fmaf(w, __uint_as_float(q.w << 16),          a1.z);
        a1.w = fmaf(w, __uint_as_float(q.w & 0xFFFF0000u),  a1.w);
    }
    float syn = butterfly8(a0, a1, sub);
    size_t idx = (size_t)n * 8 + sub;
    float vo = v_w[idx];
    float vn = vo * cf.x + syn * cf.y + cf.z;
    v_w[idx] = vn;
    r_next[idx] = (unsigned short)f2bf_rne(fmaxf(vn, 0.f));
}

__global__ void k_out(const float* __restrict__ v_w, float* __restrict__ out, int N) {
    int t = blockIdx.x * BLK + threadIdx.x;
    if (t >= NBATCH * N) return;
    int b = t / N;
    int n = t - b * N;
    out[t] = v_w[(size_t)n * 8 + b];
}

static inline size_t align16(size_t x) { return (x + 15) & ~(size_t)15; }

extern "C" void kernel_launch(void* const* d_in, const int* in_sizes, int n_in,
                              void* d_out, int out_size, void* d_ws, size_t ws_size,
                              hipStream_t stream) {
    const float* tm1_in  = (const float*)d_in[0];
    const float* v_init  = (const float*)d_in[1];
    const float* weights = (const float*)d_in[2];
    const float* bias    = (const float*)d_in[3];
    const float* tau_p   = (const float*)d_in[4];
    const float* se      = (const float*)d_in[5];
    const float* si      = (const float*)d_in[6];
    const int*   srcI    = (const int*)d_in[7];
    const int*   tgtI    = (const int*)d_in[8];
    const int*   type_ids= (const int*)d_in[9];
    const int*   tm1_idx = (const int*)d_in[10];

    const int E  = in_sizes[2];
    const int N  = in_sizes[3];
    const int NT = in_sizes[10];

    char* p = (char*)d_ws;
    size_t off = 0;
    auto take = [&](size_t bytes) { void* r = p + off; off += align16(bytes); return r; };
    int*      offsets = (int*)     take((size_t)(N + 1) * 4);
    int*      cursor  = (int*)     take((size_t)N * 4);
    int*      counts  = (int*)     take((size_t)N * 4);
    int*      tm1_pos = (int*)     take((size_t)N * 4);
    int*      bsum    = (int*)     take(1024 * 4);
    unsigned* csr     = (unsigned*)take((size_t)E * 4);
    float4*   coef    = (float4*)  take((size_t)N * 16);
    float*    v_w     = (float*)   take((size_t)N * 8 * 4);
    uint4*    r0      = (uint4*)   take((size_t)N * 16);     // bf16 rows
    uint4*    r1      = (uint4*)   take((size_t)N * 16);
    (void)ws_size;

    const int gN  = (N + BLK - 1) / BLK;
    const int gN1 = (N + 1 + BLK - 1) / BLK;
    const int gE  = (E + BLK - 1) / BLK;
    const int gNT = (NT + BLK - 1) / BLK;
    const int gS  = (N * NBATCH + BLK - 1) / BLK;

    k_zero<<<gN, BLK, 0, stream>>>(counts, tm1_pos, N);
    k_tm1pos<<<gNT, BLK, 0, stream>>>(tm1_idx, tm1_pos, NT);
    k_hist<<<gE, BLK, 0, stream>>>(tgtI, counts, E);
    k_scan1<<<gN, BLK, 0, stream>>>(counts, offsets, bsum, N);
    k_scan2<<<1, BLK, 0, stream>>>(bsum, gN);
    k_scan3<<<gN1, BLK, 0, stream>>>(bsum, offsets, cursor, N, E);
    k_fill<<<gE, BLK, 0, stream>>>(srcI, tgtI, weights, se, si, cursor, csr, E);
    k_initv<<<gN, BLK, 0, stream>>>(tm1_in, v_init, bias, tau_p, type_ids, tm1_pos,
                                    v_w, r0, r1, coef, N, NT);

    uint4* rb[2] = { r0, r1 };
    for (int s = 0; s < STEPS; ++s) {
        k_step<<<gS, BLK, 0, stream>>>(offsets, csr, coef, rb[s & 1],
                                       v_w, (unsigned short*)rb[(s + 1) & 1], N);
    }
    k_out<<<gS, BLK, 0, stream>>>(v_w, (float*)d_out, N);
}

// Round 6
// 1210.452 us; speedup vs baseline: 36.7634x; 1.0262x over previous
//
#include <hip/hip_runtime.h>

// DrosophilaOpticLobeCircuit: 100-step recurrent sparse circuit.
// R6: R5 (compressed CSR + bf16 r) with an MLP-restructured step kernel:
// three unrolled phases -- (A) 6 independent csr loads, (B) 6 independent
// row gathers, (C) FMAs -- so each lane keeps ~6 loads in flight instead of
// a serial csr->gather dependent chain per edge (R5 was latency-bound:
// VALUBusy 0.5%, HBM 0.2%, 10.4us/step).

#define BLK 256
#define STEPS 100
#define NBATCH 8
#define PRE 6              // static edge slots per lane (covers degree <= 48)
static constexpr float DT_C = 0.1f;

__device__ __forceinline__ unsigned f2bf_rne(float x) {   // fp32 -> bf16 bits (RNE)
    unsigned u = __float_as_uint(x);
    return (u + 0x7FFFu + ((u >> 16) & 1u)) >> 16;
}
__device__ __forceinline__ unsigned pk_bf2(float a, float b) {
    return f2bf_rne(a) | (f2bf_rne(b) << 16);
}

__global__ void k_zero(int* counts, int* tm1_pos, int N) {
    int i = blockIdx.x * BLK + threadIdx.x;
    if (i < N) { counts[i] = 0; tm1_pos[i] = -1; }
}

__global__ void k_tm1pos(const int* __restrict__ tm1_idx, int* tm1_pos, int NT) {
    int i = blockIdx.x * BLK + threadIdx.x;
    if (i < NT) tm1_pos[tm1_idx[i]] = i;
}

__global__ void k_hist(const int* __restrict__ tgt, int* counts, int E) {
    int i = blockIdx.x * BLK + threadIdx.x;
    if (i < E) atomicAdd(&counts[tgt[i]], 1);
}

__global__ void k_scan1(const int* __restrict__ counts, int* offsets, int* bsum, int N) {
    __shared__ int s[BLK];
    int tx = threadIdx.x;
    int i = blockIdx.x * BLK + tx;
    int v = (i < N) ? counts[i] : 0;
    s[tx] = v; __syncthreads();
    for (int d = 1; d < BLK; d <<= 1) {
        int t = (tx >= d) ? s[tx - d] : 0;
        __syncthreads();
        s[tx] += t;
        __syncthreads();
    }
    if (i < N) offsets[i] = s[tx] - v;
    if (tx == BLK - 1) bsum[blockIdx.x] = s[tx];
}

__global__ void k_scan2(int* bsum, int nb) {
    __shared__ int s[BLK];
    int tx = threadIdx.x;
    int v = (tx < nb) ? bsum[tx] : 0;
    s[tx] = v; __syncthreads();
    for (int d = 1; d < BLK; d <<= 1) {
        int t = (tx >= d) ? s[tx - d] : 0;
        __syncthreads();
        s[tx] += t;
        __syncthreads();
    }
    if (tx < nb) bsum[tx] = s[tx] - v;
}

__global__ void k_scan3(const int* __restrict__ bsum, int* offsets, int* cursor, int N, int E) {
    int i = blockIdx.x * BLK + threadIdx.x;
    if (i < N) {
        int o = offsets[i] + bsum[i >> 8];
        offsets[i] = o;
        cursor[i] = o;
    } else if (i == N) {
        offsets[N] = E;
    }
}

// CSR fill: entry = (bf16(w*scale) << 16) | src_u16
__global__ void k_fill(const int* __restrict__ srcI, const int* __restrict__ tgtI,
                       const float* __restrict__ w,
                       const float* __restrict__ se, const float* __restrict__ si,
                       int* cursor, unsigned* __restrict__ csr, int E) {
    int i = blockIdx.x * BLK + threadIdx.x;
    if (i >= E) return;
    float wv = w[i];
    float sc = wv > 0.f ? se[0] : (wv < 0.f ? si[0] : 1.f);
    float sw = wv * sc;
    unsigned entry = (f2bf_rne(sw) << 16) | (unsigned)srcI[i];
    int t = tgtI[i];
    int pos = atomicAdd(&cursor[t], 1);
    csr[pos] = entry;
}

// init v_w[N][8] (fp32), r0=r1 = bf16 rows, per-neuron coef (cA,cB,cC,tm1flag)
__global__ void k_initv(const float* __restrict__ tm1_in, const float* __restrict__ v_init,
                        const float* __restrict__ bias, const float* __restrict__ tau_p,
                        const int* __restrict__ type_ids, const int* __restrict__ tm1_pos,
                        float* __restrict__ v_w, uint4* __restrict__ r0, uint4* __restrict__ r1,
                        float4* __restrict__ coef, int N, int NT) {
    int n = blockIdx.x * BLK + threadIdx.x;
    if (n >= N) return;
    int k = tm1_pos[n];
    float tau = tau_p[type_ids[n]];
    float g = DT_C / tau;
    coef[n] = make_float4(1.f - g, g, bias[n] * g, (k >= 0) ? 1.f : 0.f);
    float vv[NBATCH], rr[NBATCH];
    for (int b = 0; b < NBATCH; ++b) {
        float val = (k >= 0) ? tm1_in[b * NT + k] : v_init[b * N + n];
        vv[b] = val;
        rr[b] = fmaxf(val, 0.f);
    }
    float4* vp = (float4*)(v_w + (size_t)n * 8);
    vp[0] = make_float4(vv[0], vv[1], vv[2], vv[3]);
    vp[1] = make_float4(vv[4], vv[5], vv[6], vv[7]);
    uint4 rq = make_uint4(pk_bf2(rr[0], rr[1]), pk_bf2(rr[2], rr[3]),
                          pk_bf2(rr[4], rr[5]), pk_bf2(rr[6], rr[7]));
    r0[n] = rq;
    r1[n] = rq;
}

// 8-lane-group butterfly transpose-reduce: a0/a1 hold 8 batch partials per
// lane; returns lane sub's full sum for batch==sub.
__device__ __forceinline__ float butterfly8(float4 a0, float4 a1, int sub) {
    int bit0 = sub & 1, bit1 = (sub >> 1) & 1, bit2 = (sub >> 2) & 1;
    float b0 = (bit0 ? a0.y : a0.x) + __shfl_xor(bit0 ? a0.x : a0.y, 1);
    float b1 = (bit0 ? a0.w : a0.z) + __shfl_xor(bit0 ? a0.z : a0.w, 1);
    float b2 = (bit0 ? a1.y : a1.x) + __shfl_xor(bit0 ? a1.x : a1.y, 1);
    float b3 = (bit0 ? a1.w : a1.z) + __shfl_xor(bit0 ? a1.z : a1.w, 1);
    float c0 = (bit1 ? b1 : b0) + __shfl_xor(bit1 ? b0 : b1, 2);
    float c1 = (bit1 ? b3 : b2) + __shfl_xor(bit1 ? b2 : b3, 2);
    return (bit2 ? c1 : c0) + __shfl_xor(bit2 ? c0 : c1, 4);
}

// one 8-lane group per target neuron; three phases for MLP:
//  A: up to PRE independent predicated csr loads -> registers
//  B: up to PRE independent predicated 16B row gathers -> registers
//  C: unpack bf16 + FMA accumulate; dynamic loop only for degree > 8*PRE.
__global__ __launch_bounds__(BLK) void k_step(
        const int* __restrict__ offsets, const unsigned* __restrict__ csr,
        const float4* __restrict__ coef, const uint4* __restrict__ r_prev,
        float* __restrict__ v_w, unsigned short* __restrict__ r_next, int N) {
    int tid = blockIdx.x * BLK + threadIdx.x;
    int n = tid >> 3;
    int sub = threadIdx.x & 7;
    if (n >= N) return;
    float4 cf = coef[n];
    if (cf.w != 0.f) return;                 // Tm1 row: clamped, r constant
    int s = offsets[n], e = offsets[n + 1];

    // phase A: csr entries (independent loads)
    float wj[PRE];
    int   sj[PRE];
    #pragma unroll
    for (int j = 0; j < PRE; ++j) {
        int idx = s + sub + 8 * j;
        unsigned ew = (idx < e) ? csr[idx] : 0u;
        wj[j] = __uint_as_float(ew & 0xFFFF0000u);   // 0 weight when inactive
        sj[j] = (int)(ew & 0xFFFFu);
    }
    // phase B: row gathers (independent loads)
    uint4 q[PRE];
    #pragma unroll
    for (int j = 0; j < PRE; ++j) {
        int idx = s + sub + 8 * j;
        q[j] = (idx < e) ? r_prev[sj[j]] : make_uint4(0u, 0u, 0u, 0u);
    }
    // phase C: unpack + accumulate
    float4 a0 = make_float4(0.f, 0.f, 0.f, 0.f);
    float4 a1 = make_float4(0.f, 0.f, 0.f, 0.f);
    #pragma unroll
    for (int j = 0; j < PRE; ++j) {
        float w = wj[j];
        a0.x = fmaf(w, __uint_as_float(q[j].x << 16),          a0.x);
        a0.y = fmaf(w, __uint_as_float(q[j].x & 0xFFFF0000u),  a0.y);
        a0.z = fmaf(w, __uint_as_float(q[j].y << 16),          a0.z);
        a0.w = fmaf(w, __uint_as_float(q[j].y & 0xFFFF0000u),  a0.w);
        a1.x = fmaf(w, __uint_as_float(q[j].z << 16),          a1.x);
        a1.y = fmaf(w, __uint_as_float(q[j].z & 0xFFFF0000u),  a1.y);
        a1.z = fmaf(w, __uint_as_float(q[j].w << 16),          a1.z);
        a1.w = fmaf(w, __uint_as_float(q[j].w & 0xFFFF0000u),  a1.w);
    }
    // rare overflow: degree > 8*PRE
    for (int i = s + sub + 8 * PRE; i < e; i += 8) {
        unsigned ew = csr[i];
        float w = __uint_as_float(ew & 0xFFFF0000u);
        uint4 qq = r_prev[ew & 0xFFFFu];
        a0.x = fmaf(w, __uint_as_float(qq.x << 16),          a0.x);
        a0.y = fmaf(w, __uint_as_float(qq.x & 0xFFFF0000u),  a0.y);
        a0.z = fmaf(w, __uint_as_float(qq.y << 16),          a0.z);
        a0.w = fmaf(w, __uint_as_float(qq.y & 0xFFFF0000u),  a0.w);
        a1.x = fmaf(w, __uint_as_float(qq.z << 16),          a1.x);
        a1.y = fmaf(w, __uint_as_float(qq.z & 0xFFFF0000u),  a1.y);
        a1.z = fmaf(w, __uint_as_float(qq.w << 16),          a1.z);
        a1.w = fmaf(w, __uint_as_float(qq.w & 0xFFFF0000u),  a1.w);
    }
    float syn = butterfly8(a0, a1, sub);
    size_t idx = (size_t)n * 8 + sub;
    float vo = v_w[idx];
    float vn = vo * cf.x + syn * cf.y + cf.z;
    v_w[idx] = vn;
    r_next[idx] = (unsigned short)f2bf_rne(fmaxf(vn, 0.f));
}

__global__ void k_out(const float* __restrict__ v_w, float* __restrict__ out, int N) {
    int t = blockIdx.x * BLK + threadIdx.x;
    if (t >= NBATCH * N) return;
    int b = t / N;
    int n = t - b * N;
    out[t] = v_w[(size_t)n * 8 + b];
}

static inline size_t align16(size_t x) { return (x + 15) & ~(size_t)15; }

extern "C" void kernel_launch(void* const* d_in, const int* in_sizes, int n_in,
                              void* d_out, int out_size, void* d_ws, size_t ws_size,
                              hipStream_t stream) {
    const float* tm1_in  = (const float*)d_in[0];
    const float* v_init  = (const float*)d_in[1];
    const float* weights = (const float*)d_in[2];
    const float* bias    = (const float*)d_in[3];
    const float* tau_p   = (const float*)d_in[4];
    const float* se      = (const float*)d_in[5];
    const float* si      = (const float*)d_in[6];
    const int*   srcI    = (const int*)d_in[7];
    const int*   tgtI    = (const int*)d_in[8];
    const int*   type_ids= (const int*)d_in[9];
    const int*   tm1_idx = (const int*)d_in[10];

    const int E  = in_sizes[2];
    const int N  = in_sizes[3];
    const int NT = in_sizes[10];

    char* p = (char*)d_ws;
    size_t off = 0;
    auto take = [&](size_t bytes) { void* r = p + off; off += align16(bytes); return r; };
    int*      offsets = (int*)     take((size_t)(N + 1) * 4);
    int*      cursor  = (int*)     take((size_t)N * 4);
    int*      counts  = (int*)     take((size_t)N * 4);
    int*      tm1_pos = (int*)     take((size_t)N * 4);
    int*      bsum    = (int*)     take(1024 * 4);
    unsigned* csr     = (unsigned*)take((size_t)E * 4);
    float4*   coef    = (float4*)  take((size_t)N * 16);
    float*    v_w     = (float*)   take((size_t)N * 8 * 4);
    uint4*    r0      = (uint4*)   take((size_t)N * 16);     // bf16 rows
    uint4*    r1      = (uint4*)   take((size_t)N * 16);
    (void)ws_size;

    const int gN  = (N + BLK - 1) / BLK;
    const int gN1 = (N + 1 + BLK - 1) / BLK;
    const int gE  = (E + BLK - 1) / BLK;
    const int gNT = (NT + BLK - 1) / BLK;
    const int gS  = (N * NBATCH + BLK - 1) / BLK;

    k_zero<<<gN, BLK, 0, stream>>>(counts, tm1_pos, N);
    k_tm1pos<<<gNT, BLK, 0, stream>>>(tm1_idx, tm1_pos, NT);
    k_hist<<<gE, BLK, 0, stream>>>(tgtI, counts, E);
    k_scan1<<<gN, BLK, 0, stream>>>(counts, offsets, bsum, N);
    k_scan2<<<1, BLK, 0, stream>>>(bsum, gN);
    k_scan3<<<gN1, BLK, 0, stream>>>(bsum, offsets, cursor, N, E);
    k_fill<<<gE, BLK, 0, stream>>>(srcI, tgtI, weights, se, si, cursor, csr, E);
    k_initv<<<gN, BLK, 0, stream>>>(tm1_in, v_init, bias, tau_p, type_ids, tm1_pos,
                                    v_w, r0, r1, coef, N, NT);

    uint4* rb[2] = { r0, r1 };
    for (int s = 0; s < STEPS; ++s) {
        k_step<<<gS, BLK, 0, stream>>>(offsets, csr, coef, rb[s & 1],
                                       v_w, (unsigned short*)rb[(s + 1) & 1], N);
    }
    k_out<<<gS, BLK, 0, stream>>>(v_w, (float*)d_out, N);
}